// Round 4
// baseline (433.622 us; speedup 1.0000x reference)
//
#include <hip/hip_runtime.h>
#include <hip/hip_bf16.h>
#include <stdint.h>

#define B 2
#define L 2048
#define D 1024
#define H 16
#define HD 64
#define NT (L / 64)          // 32 tiles of 64
#define INVALID_CID 0x40000000

typedef __hip_bfloat16 bf16;
typedef __attribute__((ext_vector_type(8))) short short8;
typedef __attribute__((ext_vector_type(4))) short short4v;
typedef __attribute__((ext_vector_type(4))) float floatx4;
typedef __attribute__((ext_vector_type(16))) float floatx16;

static __device__ __forceinline__ short f2bf(float f) {
    bf16 h = __float2bfloat16(f);
    return *reinterpret_cast<short*>(&h);
}

// async global->LDS, 16B per lane; lds base wave-uniform (HW adds lane*16)
static __device__ __forceinline__ void async_copy16(const void* g, void* l) {
    __builtin_amdgcn_global_load_lds((__attribute__((address_space(1))) void*)g,
                                     (__attribute__((address_space(3))) void*)l,
                                     16, 0, 0);
}

// ---------------------------------------------------------------- chain info
__global__ void chain_kernel(const int* __restrict__ lens,
                             float* __restrict__ pos, int* __restrict__ cid,
                             int4* __restrict__ tinfo)
{
    __shared__ int csum[L];
    __shared__ int cids[L];
    __shared__ int part[256];
    int b = blockIdx.x;
    int t = threadIdx.x;

    int loc[8];
    int s = 0;
    #pragma unroll
    for (int j = 0; j < 8; ++j) { s += lens[b * L + t * 8 + j]; loc[j] = s; }
    part[t] = s;
    __syncthreads();
    if (t == 0) {
        int acc = 0;
        for (int i = 0; i < 256; ++i) { int v = part[i]; part[i] = acc; acc += v; }
    }
    __syncthreads();
    int base = part[t];
    #pragma unroll
    for (int j = 0; j < 8; ++j) csum[t * 8 + j] = base + loc[j];
    __syncthreads();

    int total = csum[L - 1];
    for (int p = t; p < L; p += 256) {
        int cv;
        if (p < total) {
            int lo = 0, hi = L;
            while (lo < hi) {
                int mid = (lo + hi) >> 1;
                if (csum[mid] <= p) lo = mid + 1; else hi = mid;
            }
            int prev = (lo > 0) ? csum[lo - 1] : 0;
            pos[b * L + p] = (float)(p - prev);
            cv = lo;
        } else {
            pos[b * L + p] = 0.f;
            cv = INVALID_CID;
        }
        cids[p] = cv;
        cid[b * L + p] = cv;
    }
    __syncthreads();
    if (t < NT) {
        int mn = 0x7fffffff, mx = -1, any = 0, all = 1;
        for (int j = 0; j < 64; ++j) {
            int cv = cids[t * 64 + j];
            if (cv != INVALID_CID) { any = 1; mn = min(mn, cv); mx = max(mx, cv); }
            else all = 0;
        }
        tinfo[b * NT + t] = make_int4(mn, mx, any | (all << 1), 0);
    }
}

// ---------------------------------------------------------------- cast
__global__ void cast_f32_bf16(const float* __restrict__ in, bf16* __restrict__ out, int n)
{
    int i = (blockIdx.x * 256 + threadIdx.x) * 4;
    if (i + 3 < n) {
        float4 v = *(const float4*)(in + i);
        out[i + 0] = __float2bfloat16(v.x);
        out[i + 1] = __float2bfloat16(v.y);
        out[i + 2] = __float2bfloat16(v.z);
        out[i + 3] = __float2bfloat16(v.w);
    } else {
        for (; i < n; ++i) out[i] = __float2bfloat16(in[i]);
    }
}

// ---------------------------------------------------------------- GEMM (m97-style)
__global__ __launch_bounds__(256, 4) void gemm128(
    const bf16* __restrict__ A, const bf16* __restrict__ Bw,
    const float* __restrict__ bias, void* __restrict__ Cout,
    int M, int N, int K, int c_bf16)
{
    __shared__ short As[128 * 32];
    __shared__ short Bs[128 * 32];

    int tid = threadIdx.x;
    int wave = tid >> 6, lane = tid & 63;
    int i15 = lane & 15, q8 = lane >> 4;
    int wm = wave & 1, wn = wave >> 1;
    int m0 = blockIdx.y * 128, n0 = blockIdx.x * 128;

    floatx4 acc[4][4];
    #pragma unroll
    for (int mt = 0; mt < 4; ++mt)
        #pragma unroll
        for (int nt = 0; nt < 4; ++nt) acc[mt][nt] = (floatx4){0.f, 0.f, 0.f, 0.f};

    const short* gA = (const short*)A  + (size_t)(m0 + wave * 32 + (lane >> 2)) * K + (lane & 3) * 8;
    const short* gB = (const short*)Bw + (size_t)(n0 + wave * 32 + (lane >> 2)) * K + (lane & 3) * 8;
    short* lA = As + wave * 1024;
    short* lB = Bs + wave * 1024;

    for (int kt = 0; kt < K; kt += 32) {
        __syncthreads();
        async_copy16(gA + kt,          lA);
        async_copy16(gA + 16 * K + kt, lA + 512);
        async_copy16(gB + kt,          lB);
        async_copy16(gB + 16 * K + kt, lB + 512);
        __syncthreads();

        short8 af[4], bfr[4];
        #pragma unroll
        for (int mt = 0; mt < 4; ++mt)
            af[mt] = *(const short8*)&As[(wm * 64 + mt * 16 + i15) * 32 + q8 * 8];
        #pragma unroll
        for (int nt = 0; nt < 4; ++nt)
            bfr[nt] = *(const short8*)&Bs[(wn * 64 + nt * 16 + i15) * 32 + q8 * 8];
        #pragma unroll
        for (int mt = 0; mt < 4; ++mt)
            #pragma unroll
            for (int nt = 0; nt < 4; ++nt)
                acc[mt][nt] = __builtin_amdgcn_mfma_f32_16x16x32_bf16(af[mt], bfr[nt], acc[mt][nt], 0, 0, 0);
    }

    #pragma unroll
    for (int nt = 0; nt < 4; ++nt) {
        int n = n0 + wn * 64 + nt * 16 + i15;
        float bv = bias[n];
        #pragma unroll
        for (int mt = 0; mt < 4; ++mt) {
            #pragma unroll
            for (int rg = 0; rg < 4; ++rg) {
                int m = m0 + wm * 64 + mt * 16 + q8 * 4 + rg;
                float v = acc[mt][nt][rg] + bv;
                if (c_bf16) ((bf16*)Cout)[(size_t)m * N + n] = __float2bfloat16(v);
                else        ((float*)Cout)[(size_t)m * N + n] = v;
            }
        }
    }
}

// ---------------------------------------------------------------- RoPE + scatter
// Q,K -> [B,H,L,HD] (Q scaled by HD^-0.5 * log2 e); V -> [B,H,HD,L] transposed.
__global__ __launch_bounds__(256) void rope_scatter2(
    const bf16* __restrict__ qkv, const float* __restrict__ pos,
    bf16* __restrict__ Qo, bf16* __restrict__ Ko, bf16* __restrict__ Vtg)
{
    __shared__ float Vsh[64][65];
    int tid = threadIdx.x;
    int bid = blockIdx.x;
    int lt = bid & (NT - 1);
    int h  = (bid >> 5) & (H - 1);
    int b  = bid >> 9;
    int l0 = lt * 64;

    const float QSCALE = 0.18033688011111772f;  // 0.125 * log2(e)
    int hd = tid & 63, lq = tid >> 6;
    float sgn = (hd < 32) ? -1.f : 1.f;
    float invf = exp2f(-(float)(hd & 31) * (13.287712379549449f / 32.f));

    #pragma unroll
    for (int rr = 0; rr < 16; ++rr) {
        int l = l0 + lq * 16 + rr;
        size_t row = (size_t)(b * L + l) * (3 * D);
        int col  = h * HD + hd;
        int col2 = h * HD + (hd ^ 32);

        float xq  = __bfloat162float(qkv[row + col]);
        float xq2 = __bfloat162float(qkv[row + col2]);
        float xk  = __bfloat162float(qkv[row + D + col]);
        float xk2 = __bfloat162float(qkv[row + D + col2]);
        float xv  = __bfloat162float(qkv[row + 2 * D + col]);

        float p = pos[b * L + l];
        float ang = p * invf;
        float cc = cosf(ang), ss = sinf(ang);

        float qo = QSCALE * (xq * cc + sgn * xq2 * ss);
        float ko = xk * cc + sgn * xk2 * ss;

        size_t o = ((size_t)(b * H + h) * L + l) * HD + hd;
        Qo[o] = __float2bfloat16(qo);
        Ko[o] = __float2bfloat16(ko);
        Vsh[l - l0][hd] = xv;
    }
    __syncthreads();
    int lcol = tid & 63, dq = tid >> 6;
    #pragma unroll
    for (int rr = 0; rr < 16; ++rr) {
        int dd = dq * 16 + rr;
        Vtg[((size_t)(b * H + h) * HD + dd) * L + l0 + lcol] = __float2bfloat16(Vsh[lcol][dd]);
    }
}

// ---------------------------------------------------------------- attention v3: LDS-free main loop
// 4 waves = (qw,kw) quadrants of the 64q x 64k tile-pair. 32x32x16 MFMA.
// S^T = mfma(A=K_perm, B=Q): C col = query, row = key.
// Key permutation swap(bits2,3) makes S^T's C-layout == PV's A-layout (P in regs).
// Static softmax in log2 domain (Q pre-scaled by log2 e); per-kw partial O merged via LDS epilogue.
__global__ __launch_bounds__(256, 4) void attn3(
    const bf16* __restrict__ Q, const bf16* __restrict__ Kg, const bf16* __restrict__ Vtg,
    const int* __restrict__ cid, const int4* __restrict__ tinfo,
    float* __restrict__ OutF, bf16* __restrict__ OutB, const float* __restrict__ Prev,
    int branch)
{
    __shared__ float Of[2][64][65];   // [kw][query][dim], padded
    __shared__ float ls[2][64];
    __shared__ int cls_s[NT];
    __shared__ int list_s[NT];
    __shared__ int nlist_s;

    int tid = threadIdx.x;
    int wave = tid >> 6, lane = tid & 63;
    int l31 = lane & 31, l5 = lane >> 5;
    int kw = wave & 1, qw = wave >> 1;

    // XCD-aware remap: all 32 q-tiles of one (b,h) on one XCD (bid%8 heuristic)
    int bid = blockIdx.x;
    int bh_idx = (bid & 7) * 4 + ((bid >> 3) >> 5);   // 0..31
    int qt = (bid >> 3) & 31;
    int h = bh_idx & (H - 1);
    int b = bh_idx >> 4;
    int q0 = qt * 64;
    const size_t bh  = (size_t)(b * H + h) * L;
    const size_t bhd = (size_t)(b * H + h) * HD;

    // Q B-frags (4 k-chunks of HD), from global, once
    short8 qf[4];
    {
        const short* qp = (const short*)Q + (bh + q0 + qw * 32 + l31) * HD + l5 * 8;
        #pragma unroll
        for (int c = 0; c < 4; ++c) qf[c] = *(const short8*)(qp + c * 16);
    }
    int cq = cid[b * L + q0 + qw * 32 + l31];

    int4 qinf = tinfo[b * NT + qt];
    int qall = (qinf.z >> 1) & 1;

    if (tid < NT) {
        int4 ki = tinfo[b * NT + tid];
        int kany = ki.z & 1, kall = (ki.z >> 1) & 1;
        bool disjoint = (ki.x > qinf.y) || (ki.y < qinf.x);
        bool mono = qall && kall && (qinf.x == qinf.y) && (ki.x == ki.y) && (qinf.x == ki.x);
        int cls;
        if (branch == 0) {
            if (!kany || disjoint) cls = 0;
            else if (mono) cls = 2;
            else cls = 1;
        } else {
            if (!kany || mono) cls = 0;
            else if (kall && disjoint) cls = 2;
            else cls = 1;
        }
        cls_s[tid] = cls;
    }
    __syncthreads();
    if (tid == 0) {
        int n = 0;
        for (int t = 0; t < NT; ++t) {
            int c = cls_s[t];
            if (c) list_s[n++] = (t * 64) | ((c == 2) << 16);
        }
        nlist_s = n;
    }
    __syncthreads();
    int n = nlist_s;

    // permuted key index: swap bits 2 and 3 of l31
    int kidx = (l31 & 0x13) | ((l31 & 4) << 1) | ((l31 & 8) >> 1);
    const short* kbase = (const short*)Kg  + (bh + kw * 32 + kidx) * HD + l5 * 8;
    const short* vbase = (const short*)Vtg + (bhd + l31) * L + kw * 32 + l5 * 8;

    floatx16 accO[2];
    #pragma unroll
    for (int r = 0; r < 16; ++r) { accO[0][r] = 0.f; accO[1][r] = 0.f; }
    float lsum = 0.f;

    for (int it = 0; it < n; ++it) {
        int cur = list_s[it];
        int kt = cur & 0xffff, full = cur >> 16;

        // K fragments (permuted rows), V^T fragments — straight from global (L1/L2)
        short8 kf[4], vf[2][2];
        {
            const short* kp = kbase + (size_t)kt * HD;
            #pragma unroll
            for (int c = 0; c < 4; ++c) kf[c] = *(const short8*)(kp + c * 16);
            #pragma unroll
            for (int dt = 0; dt < 2; ++dt)
                #pragma unroll
                for (int c = 0; c < 2; ++c)
                    vf[dt][c] = *(const short8*)(vbase + (size_t)dt * 32 * L + kt + c * 16);
        }

        // S^T = K_perm^T-rows x Q: rows=keys(permuted), cols=queries
        floatx16 accS;
        #pragma unroll
        for (int r = 0; r < 16; ++r) accS[r] = 0.f;
        #pragma unroll
        for (int c = 0; c < 4; ++c)
            accS = __builtin_amdgcn_mfma_f32_32x32x16_bf16(kf[c], qf[c], accS, 0, 0, 0);

        if (!full) {
            #pragma unroll
            for (int g = 0; g < 4; ++g) {
                // true keys for regs 4g..4g+3 (contiguous after the bit-swap)
                int koff = kt + kw * 32 + 4 * (g & 1) + 8 * l5 + 16 * (g >> 1);
                int4 kc = *(const int4*)&cid[b * L + koff];
                int ckk[4] = {kc.x, kc.y, kc.z, kc.w};
                #pragma unroll
                for (int j = 0; j < 4; ++j) {
                    bool kv = (ckk[j] != INVALID_CID);
                    bool match = (cq == ckk[j]);
                    bool ok = kv && (branch ? !match : match);
                    int r = g * 4 + j;
                    accS[r] = ok ? accS[r] : -1e30f;
                }
            }
        }

        // P = 2^S in registers; C-layout == A-layout thanks to key permutation
        short p16[16];
        #pragma unroll
        for (int r = 0; r < 16; ++r) {
            float p = __builtin_amdgcn_exp2f(accS[r]);
            lsum += p;
            p16[r] = f2bf(p);
        }
        short8 pf0 = {p16[0], p16[1], p16[2],  p16[3],  p16[4],  p16[5],  p16[6],  p16[7]};
        short8 pf1 = {p16[8], p16[9], p16[10], p16[11], p16[12], p16[13], p16[14], p16[15]};

        #pragma unroll
        for (int dt = 0; dt < 2; ++dt) {
            accO[dt] = __builtin_amdgcn_mfma_f32_32x32x16_bf16(pf0, vf[dt][0], accO[dt], 0, 0, 0);
            accO[dt] = __builtin_amdgcn_mfma_f32_32x32x16_bf16(pf1, vf[dt][1], accO[dt], 0, 0, 0);
        }
    }

    // merge kw halves via LDS
    lsum += __shfl_xor(lsum, 32, 64);       // query l31's 32-key sum for this kw half
    if (l5 == 0) ls[kw][qw * 32 + l31] = lsum;
    #pragma unroll
    for (int dt = 0; dt < 2; ++dt)
        #pragma unroll
        for (int r = 0; r < 16; ++r) {
            int q = (r & 3) + 8 * (r >> 2) + 4 * l5;
            Of[kw][qw * 32 + q][dt * 32 + l31] = accO[dt][r];
        }
    __syncthreads();

    int q = tid & 63, dg = tid >> 6;
    float lt2 = ls[0][q] + ls[1][q];
    float invl = (lt2 > 0.f) ? 1.f / lt2 : 0.f;
    #pragma unroll
    for (int v = 0; v < 4; ++v) {
        int d = dg * 16 + v * 4;
        float4 o0 = *(const float4*)&Of[0][q][d];
        float4 o1 = *(const float4*)&Of[1][q][d];
        size_t idx = (size_t)(b * L + q0 + q) * D + h * HD + d;
        float ox = (o0.x + o1.x) * invl, oy = (o0.y + o1.y) * invl;
        float oz = (o0.z + o1.z) * invl, ow = (o0.w + o1.w) * invl;
        if (branch == 0) {
            *(float4*)&OutF[idx] = make_float4(ox, oy, oz, ow);
        } else {
            float4 pv = *(const float4*)&Prev[idx];
            short4v st = {f2bf(ox + pv.x), f2bf(oy + pv.y), f2bf(oz + pv.z), f2bf(ow + pv.w)};
            *(short4v*)&OutB[idx] = st;
        }
    }
}

// ---------------------------------------------------------------- launch
extern "C" void kernel_launch(void* const* d_in, const int* in_sizes, int n_in,
                              void* d_out, int out_size, void* d_ws, size_t ws_size,
                              hipStream_t stream)
{
    const float* x    = (const float*)d_in[0];
    const int*   mlen = (const int*)  d_in[1];
    const float* Wi   = (const float*)d_in[2];
    const float* bi   = (const float*)d_in[3];
    const float* We   = (const float*)d_in[4];
    const float* be   = (const float*)d_in[5];
    const float* Wo   = (const float*)d_in[6];
    const float* bo   = (const float*)d_in[7];

    char* ws = (char*)d_ws;
    size_t off = 0;
    auto alloc = [&](size_t bytes) {
        void* p = ws + off;
        off += (bytes + 255) & ~(size_t)255;
        return p;
    };
    bf16*  x_b   = (bf16*) alloc((size_t)B * L * D * 2);
    bf16*  Wi_b  = (bf16*) alloc((size_t)3 * D * D * 2);
    bf16*  We_b  = (bf16*) alloc((size_t)3 * D * D * 2);
    bf16*  Wo_b  = (bf16*) alloc((size_t)D * D * 2);
    bf16*  qkv_b = (bf16*) alloc((size_t)B * L * 3 * D * 2);
    bf16*  q_b   = (bf16*) alloc((size_t)B * H * L * HD * 2);
    bf16*  k_b   = (bf16*) alloc((size_t)B * H * L * HD * 2);
    bf16*  vt_b  = (bf16*) alloc((size_t)B * H * HD * L * 2);
    float* att_i = (float*)alloc((size_t)B * L * D * 4);
    bf16*  sum_b = (bf16*) alloc((size_t)B * L * D * 2);
    float* pos   = (float*)alloc((size_t)B * L * 4);
    int*   cid   = (int*)  alloc((size_t)B * L * 4);
    int4*  tinfo = (int4*) alloc((size_t)B * NT * 16);
    (void)ws_size; (void)n_in; (void)in_sizes; (void)out_size;

    chain_kernel<<<B, 256, 0, stream>>>(mlen, pos, cid, tinfo);

    int nx = B * L * D;
    int nw = 3 * D * D;
    cast_f32_bf16<<<(nx / 4 + 255) / 256, 256, 0, stream>>>(x, x_b, nx);
    cast_f32_bf16<<<(nw / 4 + 255) / 256, 256, 0, stream>>>(Wi, Wi_b, nw);
    cast_f32_bf16<<<(nw / 4 + 255) / 256, 256, 0, stream>>>(We, We_b, nw);
    cast_f32_bf16<<<(D * D / 4 + 255) / 256, 256, 0, stream>>>(Wo, Wo_b, D * D);

    dim3 gq(3 * D / 128, B * L / 128);
    gemm128<<<gq, 256, 0, stream>>>(x_b, Wi_b, bi, qkv_b, B * L, 3 * D, D, 1);
    rope_scatter2<<<B * H * NT, 256, 0, stream>>>(qkv_b, pos, q_b, k_b, vt_b);
    attn3<<<B * H * NT, 256, 0, stream>>>(q_b, k_b, vt_b, cid, tinfo, att_i, sum_b, att_i, 0);

    gemm128<<<gq, 256, 0, stream>>>(x_b, We_b, be, qkv_b, B * L, 3 * D, D, 1);
    rope_scatter2<<<B * H * NT, 256, 0, stream>>>(qkv_b, pos, q_b, k_b, vt_b);
    attn3<<<B * H * NT, 256, 0, stream>>>(q_b, k_b, vt_b, cid, tinfo, att_i, sum_b, att_i, 1);

    dim3 go(D / 128, B * L / 128);
    gemm128<<<go, 256, 0, stream>>>(sum_b, Wo_b, bo, d_out, B * L, D, D, 0);
}